// Round 10
// baseline (147.199 us; speedup 1.0000x reference)
//
#include <hip/hip_runtime.h>
#include <math.h>

typedef _Float16 half8 __attribute__((ext_vector_type(8)));
typedef float f32x4 __attribute__((ext_vector_type(4)));

// dims
constexpr int B_ = 8;
constexpr int HG = 160, WG = 320;          // guidance spatial
constexpr int H = 80, W = 160;             // x spatial
// ws layout (bytes)
constexpr size_t CWS_OFF  = 0;             // 8 ng * 92160 = 737280
constexpr size_t W1WS_OFF = 737280;        // 9 taps * 4096 = 36864
constexpr size_t XG_OFF   = 774144;        // 8*80*160*64*2 = 13107200
constexpr size_t CNT_OFF  = 13881344;      // 4 B work-stealing counter

// ---------------------------------------------------------------------------
// prep: weight tensors -> MFMA B-operand register images.
// conv2 NEW (k-paired-lane layout): Cws [ng 8][18 s][5 f][1024B].
//   n = k*64 + ij (k<9, ij<64); ng = ij>>3, ijl = ij&7; f = k>>1, kp = k&1;
//   col cc = ijl*2 + kp. Fragment image: lane = grp*16 + cc holds
//   B[kl = grp*8 + j][cc], j=0..7 f16 at byte lane*16 + j*2.
//   K = t*64 + cin -> s = 2t + (cin>>5), kl = cin&31.
//   Pad: frag 4 odd cols (would-be k=9) zero-filled.
// conv1: w1ws [t=9][nt 4][1024B] unchanged from R8/R9.
// ---------------------------------------------------------------------------
__global__ __launch_bounds__(256) void prep(const float* __restrict__ w1,
                                            const float* __restrict__ w2,
                                            char* __restrict__ ws)
{
    int e = blockIdx.x * 256 + threadIdx.x;
    if (e < 576 * 64) {
        int n = e >> 6, cin = e & 63;
        int k = n >> 6;                       // 0..8
        int ij = n & 63;
        int ng = ij >> 3, ijl = ij & 7;
        int f = k >> 1, kp = k & 1;
        int cc = ijl * 2 + kp;                // col 0..15
        int grp = (cin & 31) >> 3, j = cin & 7;
        int c5 = cin >> 5;
        const float* src = w2 + ((size_t)(n * 64 + cin)) * 9;
        size_t base = CWS_OFF + (size_t)ng * 92160 + (size_t)f * 1024
                    + (grp * 16 + cc) * 16 + j * 2;
#pragma unroll
        for (int t = 0; t < 9; ++t) {
            int s = t * 2 + c5;
            *(_Float16*)(ws + base + (size_t)s * 5120) = (_Float16)src[t];
        }
    } else if (e < 576 * 64 + 64 * 32) {
        int e2 = e - 576 * 64;
        int ch = e2 >> 5, cin = e2 & 31;
        const float* src = w1 + ((size_t)(ch * 32 + cin)) * 9;
        int fragoff = (ch >> 4) * 1024 + ((cin >> 3) * 16 + (ch & 15)) * 16 + (cin & 7) * 2;
#pragma unroll
        for (int t = 0; t < 9; ++t)
            *(_Float16*)(ws + W1WS_OFF + (size_t)t * 4096 + fragoff) = (_Float16)src[t];
    } else if (e < 576 * 64 + 64 * 32 + 4608) {
        // zero-fill pad: frag 4, odd cols, all (ng, s)
        int e3 = e - (576 * 64 + 64 * 32);
        int ng = e3 / 576, rem = e3 - ng * 576;
        int s = rem >> 5, idx = rem & 31;
        int grp = idx >> 3, codd = ((idx & 7) << 1) | 1;
        half8 z;
#pragma unroll
        for (int q = 0; q < 8; ++q) z[q] = (_Float16)0.f;
        *(half8*)(ws + CWS_OFF + (size_t)ng * 92160 + (size_t)s * 5120
                  + 4 * 1024 + (grp * 16 + codd) * 16) = z;
    }
}

// ---------------------------------------------------------------------------
// conv1 (3x3 s2 p1, 32->64) + BN + ReLU via MFMA. Output f16 NHWC.
// (unchanged from R8/R9 — register-direct weights, no K-loop barriers)
// ---------------------------------------------------------------------------
__global__ __launch_bounds__(256, 4) void conv1_mfma(
    const float* __restrict__ g, const char* __restrict__ ws_w1,
    const float* __restrict__ gamma, const float* __restrict__ beta,
    const float* __restrict__ mean, const float* __restrict__ var,
    _Float16* __restrict__ xg)
{
    const int tx0 = blockIdx.x * 16, ty0 = blockIdx.y * 8, b = blockIdx.z;
    __shared__ __align__(16) _Float16 gl[2][17][18][32];   // 39168 B
    const int tid = threadIdx.x;

    const int gy0 = 2 * ty0 - 1;
    const int gxa0 = 2 * tx0 - 2;
    for (int i = tid; i < 17 * 32 * 17; i += 256) {
        int wr = i / 544; int rem = i - wr * 544;
        int cin = rem / 17; int c2 = rem - cin * 17;
        int gy = gy0 + wr;
        int gxa = gxa0 + 2 * c2;
        float2 v = make_float2(0.f, 0.f);
        if (gy >= 0 && gy < HG && gxa >= 0)
            v = *(const float2*)(g + ((size_t)(b * 32 + cin) * HG + gy) * WG + gxa);
        int slot = cin >> 3, elem = cin & 7;
        if (c2 > 0) {
            int wch = c2 - 1;
            gl[1][wr][wch][((slot ^ ((wch >> 1) & 3)) << 3) + elem] = (_Float16)v.x;
        }
        {
            int wch = c2;
            gl[0][wr][wch][((slot ^ ((wch >> 1) & 3)) << 3) + elem] = (_Float16)v.y;
        }
    }

    const int lane = tid & 63, w = tid >> 6;
    const int c = lane & 15, grp = lane >> 4;

    const _Float16* w1p = (const _Float16*)ws_w1 + lane * 8;
    half8 bf[4];
#pragma unroll
    for (int nt = 0; nt < 4; ++nt) bf[nt] = *(const half8*)(w1p + nt * 512);

    f32x4 zf = {0.f, 0.f, 0.f, 0.f};
    f32x4 acc[2][4];
#pragma unroll
    for (int mt = 0; mt < 2; ++mt)
#pragma unroll
        for (int nt = 0; nt < 4; ++nt) acc[mt][nt] = zf;

    __syncthreads();   // gl ready; no further barriers

#pragma unroll
    for (int s = 0; s < 9; ++s) {
        const int dy = s / 3, dx = s - dy * 3;
        const int par = dx & 1, dxh = dx >> 1;
        half8 af[2];
#pragma unroll
        for (int mt = 0; mt < 2; ++mt) {
            int wr = 2 * (2 * w + mt) + dy;
            int wch = c + dxh;
            af[mt] = *(const half8*)&gl[par][wr][wch][(grp ^ ((wch >> 1) & 3)) << 3];
        }
        const _Float16* wnext = w1p + (size_t)(s + 1) * 2048;
#pragma unroll
        for (int nt = 0; nt < 4; ++nt) {
            half8 cur = bf[nt];
            bf[nt] = *(const half8*)(wnext + nt * 512);   // s=8 overread harmless
            acc[0][nt] = __builtin_amdgcn_mfma_f32_16x16x32_f16(af[0], cur, acc[0][nt], 0, 0, 0);
            acc[1][nt] = __builtin_amdgcn_mfma_f32_16x16x32_f16(af[1], cur, acc[1][nt], 0, 0, 0);
        }
    }

#pragma unroll
    for (int nt = 0; nt < 4; ++nt) {
        int ch = nt * 16 + c;
        float mu = mean[ch], scv = rsqrtf(var[ch] + 1e-5f) * gamma[ch], bt = beta[ch];
#pragma unroll
        for (int mt = 0; mt < 2; ++mt) {
            int y = ty0 + 2 * w + mt;
#pragma unroll
            for (int r = 0; r < 4; ++r) {
                int x = tx0 + grp * 4 + r;
                float v = fmaxf((acc[mt][nt][r] - mu) * scv + bt, 0.f);
                xg[(((size_t)(b * H + y) * W + x) << 6) + ch] = (_Float16)v;
            }
        }
    }
}

// ---------------------------------------------------------------------------
// conv2 (3x3 s1 p1, 64->576) + softmax(9) + convex combine + pixel shuffle.
// K-PAIRED-LANE layout: each lane owns (ijl = c>>1, k-parity = c&1); 5 B-
// fragments per K-step (frag4 odd cols zero-pad). acc[4][5] = 80 regs ->
// 3 waves/SIMD (__launch_bounds__(256,3)). Softmax per (px, ij) combines a
// lane pair via ds_swizzle xor-1. Register-direct B stream, no K-loop
// barriers. 3200 steal-tiles = 1600 px-tiles x 2 ng-halves; wave ng = h*4+wid.
// ---------------------------------------------------------------------------
__global__ __launch_bounds__(256, 3) void conv2_mfma(
    const _Float16* __restrict__ xg, const char* __restrict__ ws_c,
    const float* __restrict__ disp, float* __restrict__ out,
    int* __restrict__ cnt)
{
    __shared__ __align__(16) _Float16 xs[108 * 64];   // 6r x 18c x 64ch, 13824 B
    __shared__ float d8s[108];
    __shared__ int s_tile;
    const int tid = threadIdx.x;
    const int lane = tid & 63, wid = tid >> 6;
    const int c = lane & 15, grp = lane >> 4;
    const int kp = c & 1, ijl = c >> 1;

    half8 zero8;
#pragma unroll
    for (int j = 0; j < 8; ++j) zero8[j] = (_Float16)0.f;

    for (;;) {
        if (tid == 0) s_tile = atomicAdd(cnt, 1);
        __syncthreads();   // broadcast tile; also guards xs/d8s reuse
        const int tile = __builtin_amdgcn_readfirstlane(s_tile);
        if (tile >= 3200) break;
        const int pxt = tile >> 1, h = tile & 1;
        const int b   = pxt / 200;
        const int rem = pxt - b * 200;
        const int tyi = rem / 10;
        const int tx0 = (rem - tyi * 10) * 16, ty0 = tyi * 4;
        const int ng  = h * 4 + wid;

        // stage x window 6x18x64 f16, swizzled: 16B slot' = slot ^ (wp&7)
        for (int cidx = tid; cidx < 864; cidx += 256) {
            int wpx = cidx >> 3, slot = cidx & 7;
            int rr = wpx / 18, cc2 = wpx - rr * 18;
            int y = ty0 - 1 + rr, xc = tx0 - 1 + cc2;
            half8 v = zero8;
            if (y >= 0 && y < H && xc >= 0 && xc < W)
                v = *(const half8*)(xg + (((size_t)(b * H + y) * W + xc) << 6) + slot * 8);
            *(half8*)&xs[wpx * 64 + (slot ^ (wpx & 7)) * 8] = v;
        }
        if (tid < 108) {
            int rr = tid / 18, cc2 = tid - rr * 18;
            int y = ty0 - 1 + rr, xc = tx0 - 1 + cc2;
            float v = 0.f;
            if (y >= 0 && y < H && xc >= 0 && xc < W) v = 8.f * disp[(b * H + y) * W + xc];
            d8s[tid] = v;
        }

        f32x4 zf = {0.f, 0.f, 0.f, 0.f};
        f32x4 acc[4][5];
#pragma unroll
        for (int m = 0; m < 4; ++m)
#pragma unroll
            for (int f = 0; f < 5; ++f) acc[m][f] = zf;

        // this wave's weight stream: [18 s][5 f][1024B], lane slice = lane*16 B
        const _Float16* wp = (const _Float16*)ws_c + (size_t)ng * 46080 + lane * 8;

        half8 bf[5];
#pragma unroll
        for (int f = 0; f < 5; ++f) bf[f] = *(const half8*)(wp + f * 512);

        __syncthreads();   // xs, d8s ready

#pragma unroll 2
        for (int s = 0; s < 18; ++s) {
            const int t = s >> 1;
            const int dy = t / 3, dx = t - dy * 3;
            const int aslot = (s & 1) * 4 + grp;
            half8 af[4];
#pragma unroll
            for (int mt = 0; mt < 4; ++mt) {
                int wrow = (mt + dy) * 18 + c + dx;
                af[mt] = *(const half8*)&xs[wrow * 64 + (aslot ^ (wrow & 7)) * 8];
            }
            const _Float16* wnext = wp + (size_t)(s + 1) * 2560;
#pragma unroll
            for (int f = 0; f < 5; ++f) {
                half8 cur = bf[f];
                // prefetch step s+1 frag f (s=17 overreads into w1ws: harmless)
                bf[f] = *(const half8*)(wnext + f * 512);
#pragma unroll
                for (int mt = 0; mt < 4; ++mt)
                    acc[mt][f] = __builtin_amdgcn_mfma_f32_16x16x32_f16(
                        af[mt], cur, acc[mt][f], 0, 0, 0);
            }
        }

        // epilogue: per (px, ij) softmax over 9 k split across a lane pair
        // (this lane: k = 2f + kp; partner lane^1 has the other parity).
        const int oi = ng;               // ij = ng*8 + ijl -> oi = ng, oj = ijl
        const int oj = ijl;
        const bool v4 = (kp == 0);       // frag 4 valid only for even parity (k=8)
#pragma unroll
        for (int mt = 0; mt < 4; ++mt) {
#pragma unroll
            for (int r = 0; r < 4; ++r) {
                const int pc = grp * 4 + r;
                float a4 = v4 ? acc[mt][4][r] : -3.0e38f;
                float mxo = fmaxf(fmaxf(fmaxf(acc[mt][0][r], acc[mt][1][r]),
                                        fmaxf(acc[mt][2][r], acc[mt][3][r])), a4);
                float oth = __int_as_float(__builtin_amdgcn_ds_swizzle(
                    __float_as_int(mxo), 0x041F));
                float mx = fmaxf(mxo, oth);
                float so = 0.f, uo = 0.f;
#pragma unroll
                for (int f = 0; f < 5; ++f) {
                    int k = 2 * f + kp;
                    int kk = (k < 9) ? k : 8;
                    float e = __expf(acc[mt][f][r] - mx);
                    if (f == 4) e = v4 ? e : 0.f;
                    float pkf = d8s[(mt + kk / 3) * 18 + pc + kk % 3];
                    so += e; uo += e * pkf;
                }
                float sum = so + __int_as_float(__builtin_amdgcn_ds_swizzle(
                    __float_as_int(so), 0x041F));
                float up  = uo + __int_as_float(__builtin_amdgcn_ds_swizzle(
                    __float_as_int(uo), 0x041F));
                if (kp == 0) {
                    int y = ty0 + mt, xc = tx0 + pc;
                    out[((size_t)(b * (8 * H) + y * 8 + oi)) * (size_t)(8 * W)
                        + xc * 8 + oj] = up / sum;
                }
            }
        }
        // next loop-top __syncthreads guards xs/d8s overwrite
    }
}

// ---------------------------------------------------------------------------
extern "C" void kernel_launch(void* const* d_in, const int* in_sizes, int n_in,
                              void* d_out, int out_size, void* d_ws, size_t ws_size,
                              hipStream_t stream)
{
    const float* guidance = (const float*)d_in[0];
    const float* disp     = (const float*)d_in[1];
    const float* conv1_w  = (const float*)d_in[2];
    const float* bn_gamma = (const float*)d_in[3];
    const float* bn_beta  = (const float*)d_in[4];
    const float* bn_mean  = (const float*)d_in[5];
    const float* bn_var   = (const float*)d_in[6];
    const float* conv2_w  = (const float*)d_in[7];
    float* out = (float*)d_out;
    char* ws = (char*)d_ws;
    _Float16* xg = (_Float16*)(ws + XG_OFF);
    int* cnt = (int*)(ws + CNT_OFF);

    hipMemsetAsync(cnt, 0, sizeof(int), stream);   // reset stealing counter
    prep<<<dim3((576 * 64 + 64 * 32 + 4608 + 255) / 256), dim3(256), 0, stream>>>(
        conv1_w, conv2_w, ws);
    dim3 grid1(W / 16, H / 8, B_);   // (10, 10, 8)
    conv1_mfma<<<grid1, dim3(256), 0, stream>>>(
        guidance, ws + W1WS_OFF, bn_gamma, bn_beta, bn_mean, bn_var, xg);
    conv2_mfma<<<dim3(1536), dim3(256), 0, stream>>>(
        xg, ws + CWS_OFF, disp, out, cnt);
}

// Round 11
// 110.786 us; speedup vs baseline: 1.3287x; 1.3287x over previous
//
#include <hip/hip_runtime.h>
#include <math.h>

typedef _Float16 half8 __attribute__((ext_vector_type(8)));
typedef float f32x4 __attribute__((ext_vector_type(4)));

// dims
constexpr int B_ = 8;
constexpr int HG = 160, WG = 320;          // guidance spatial
constexpr int H = 80, W = 160;             // x spatial
// ws layout (bytes)
constexpr size_t CWS_OFF  = 0;             // 4 ng * 165888 = 663552
constexpr size_t W1WS_OFF = 663552;        // 9 taps * 4096 = 36864
constexpr size_t XG_OFF   = 700416;        // 8*80*160*64*2 = 13107200

// ---------------------------------------------------------------------------
// prep: weight tensors -> MFMA B-operand register images (one thread per
// (n, cin), reading 9 contiguous taps).   (R8 version, unchanged)
// conv2: Cws [ng][18 s][9 k][1024B]; lane = grp*16+nl (grp=kl>>3, nl=n&15)
//   holds bytes [lane*16,lane*16+16) = kl j=grp*8..+8. K = t*64+cin ->
//   s = 2t + (cin>>5), kl = cin&31.
// conv1: w1ws [t=9][nt 4][1024B]; same image with kl=cin(32), nl=ch&15.
// ---------------------------------------------------------------------------
__global__ __launch_bounds__(256) void prep(const float* __restrict__ w1,
                                            const float* __restrict__ w2,
                                            char* __restrict__ ws)
{
    int e = blockIdx.x * 256 + threadIdx.x;
    if (e < 576 * 64) {
        int n = e >> 6, cin = e & 63;
        int k = n >> 6, ng = (n >> 4) & 3, nl = n & 15;
        int kl = cin & 31, c5 = cin >> 5;
        const float* src = w2 + ((size_t)(n * 64 + cin)) * 9;
        int fragoff = ((kl >> 3) * 16 + nl) * 16 + (kl & 7) * 2;
#pragma unroll
        for (int t = 0; t < 9; ++t) {
            int s = t * 2 + c5;
            *(_Float16*)(ws + CWS_OFF + (size_t)ng * 165888
                         + (size_t)(s * 9 + k) * 1024 + fragoff) = (_Float16)src[t];
        }
    } else if (e < 576 * 64 + 64 * 32) {
        int e2 = e - 576 * 64;
        int ch = e2 >> 5, cin = e2 & 31;
        const float* src = w1 + ((size_t)(ch * 32 + cin)) * 9;
        int fragoff = (ch >> 4) * 1024 + ((cin >> 3) * 16 + (ch & 15)) * 16 + (cin & 7) * 2;
#pragma unroll
        for (int t = 0; t < 9; ++t)
            *(_Float16*)(ws + W1WS_OFF + (size_t)t * 4096 + fragoff) = (_Float16)src[t];
    }
}

// ---------------------------------------------------------------------------
// conv1 (3x3 s2 p1, 32->64) + BN + ReLU via MFMA. Output f16 NHWC.
// (R8 version, unchanged — register-direct weights, no K-loop barriers,
// parity-split XOR-swizzled guidance LDS, 4 blocks/CU)
// ---------------------------------------------------------------------------
__global__ __launch_bounds__(256, 4) void conv1_mfma(
    const float* __restrict__ g, const char* __restrict__ ws_w1,
    const float* __restrict__ gamma, const float* __restrict__ beta,
    const float* __restrict__ mean, const float* __restrict__ var,
    _Float16* __restrict__ xg)
{
    const int tx0 = blockIdx.x * 16, ty0 = blockIdx.y * 8, b = blockIdx.z;
    __shared__ __align__(16) _Float16 gl[2][17][18][32];   // 39168 B
    const int tid = threadIdx.x;

    const int gy0 = 2 * ty0 - 1;
    const int gxa0 = 2 * tx0 - 2;
    for (int i = tid; i < 17 * 32 * 17; i += 256) {
        int wr = i / 544; int rem = i - wr * 544;
        int cin = rem / 17; int c2 = rem - cin * 17;
        int gy = gy0 + wr;
        int gxa = gxa0 + 2 * c2;
        float2 v = make_float2(0.f, 0.f);
        if (gy >= 0 && gy < HG && gxa >= 0)
            v = *(const float2*)(g + ((size_t)(b * 32 + cin) * HG + gy) * WG + gxa);
        int slot = cin >> 3, elem = cin & 7;
        if (c2 > 0) {
            int wch = c2 - 1;
            gl[1][wr][wch][((slot ^ ((wch >> 1) & 3)) << 3) + elem] = (_Float16)v.x;
        }
        {
            int wch = c2;
            gl[0][wr][wch][((slot ^ ((wch >> 1) & 3)) << 3) + elem] = (_Float16)v.y;
        }
    }

    const int lane = tid & 63, w = tid >> 6;
    const int c = lane & 15, grp = lane >> 4;

    const _Float16* w1p = (const _Float16*)ws_w1 + lane * 8;
    half8 bf[4];
#pragma unroll
    for (int nt = 0; nt < 4; ++nt) bf[nt] = *(const half8*)(w1p + nt * 512);

    f32x4 zf = {0.f, 0.f, 0.f, 0.f};
    f32x4 acc[2][4];
#pragma unroll
    for (int mt = 0; mt < 2; ++mt)
#pragma unroll
        for (int nt = 0; nt < 4; ++nt) acc[mt][nt] = zf;

    __syncthreads();   // gl ready; no further barriers

#pragma unroll
    for (int s = 0; s < 9; ++s) {
        const int dy = s / 3, dx = s - dy * 3;
        const int par = dx & 1, dxh = dx >> 1;
        half8 af[2];
#pragma unroll
        for (int mt = 0; mt < 2; ++mt) {
            int wr = 2 * (2 * w + mt) + dy;
            int wch = c + dxh;
            af[mt] = *(const half8*)&gl[par][wr][wch][(grp ^ ((wch >> 1) & 3)) << 3];
        }
        const _Float16* wnext = w1p + (size_t)(s + 1) * 2048;
#pragma unroll
        for (int nt = 0; nt < 4; ++nt) {
            half8 cur = bf[nt];
            bf[nt] = *(const half8*)(wnext + nt * 512);   // s=8 overread harmless
            acc[0][nt] = __builtin_amdgcn_mfma_f32_16x16x32_f16(af[0], cur, acc[0][nt], 0, 0, 0);
            acc[1][nt] = __builtin_amdgcn_mfma_f32_16x16x32_f16(af[1], cur, acc[1][nt], 0, 0, 0);
        }
    }

#pragma unroll
    for (int nt = 0; nt < 4; ++nt) {
        int ch = nt * 16 + c;
        float mu = mean[ch], scv = rsqrtf(var[ch] + 1e-5f) * gamma[ch], bt = beta[ch];
#pragma unroll
        for (int mt = 0; mt < 2; ++mt) {
            int y = ty0 + 2 * w + mt;
#pragma unroll
            for (int r = 0; r < 4; ++r) {
                int x = tx0 + grp * 4 + r;
                float v = fmaxf((acc[mt][nt][r] - mu) * scv + bt, 0.f);
                xg[(((size_t)(b * H + y) * W + x) << 6) + ch] = (_Float16)v;
            }
        }
    }
}

// ---------------------------------------------------------------------------
// conv2 (3x3 s1 p1, 64->576) + softmax(9) + convex combine + pixel shuffle.
// R7 engine (64 px / 4 waves / register-direct B / no K-loop barriers /
// static 1600-block grid) + RING-OFFSET K-loop: each block starts its K-step
// ring at s0 = (lb*7) % 18 (sum over K is order-invariant), desynchronizing
// co-resident blocks' MFMA bursts and load windows on each SIMD.
// ---------------------------------------------------------------------------
__global__ __launch_bounds__(256, 2) void conv2_mfma(
    const _Float16* __restrict__ xg, const char* __restrict__ ws_c,
    const float* __restrict__ disp, float* __restrict__ out)
{
    const int tx0 = blockIdx.x * 16, ty0 = blockIdx.y * 4, b = blockIdx.z;
    __shared__ __align__(16) _Float16 xs[108 * 64];   // 6r x 18c x 64ch, 13824 B
    __shared__ float d8s[108];
    const int tid = threadIdx.x;
    const int lane = tid & 63, wid = tid >> 6;
    const int c = lane & 15, grp = lane >> 4;

    // stage x window 6x18x64 f16, swizzled: 16B slot' = slot ^ (wp&7)
    half8 zero8;
#pragma unroll
    for (int j = 0; j < 8; ++j) zero8[j] = (_Float16)0.f;
    for (int cidx = tid; cidx < 864; cidx += 256) {
        int wpx = cidx >> 3, slot = cidx & 7;
        int rr = wpx / 18, cc = wpx - rr * 18;
        int y = ty0 - 1 + rr, xc = tx0 - 1 + cc;
        half8 v = zero8;
        if (y >= 0 && y < H && xc >= 0 && xc < W)
            v = *(const half8*)(xg + (((size_t)(b * H + y) * W + xc) << 6) + slot * 8);
        *(half8*)&xs[wpx * 64 + (slot ^ (wpx & 7)) * 8] = v;
    }
    if (tid < 108) {
        int rr = tid / 18, cc = tid - rr * 18;
        int y = ty0 - 1 + rr, xc = tx0 - 1 + cc;
        float v = 0.f;
        if (y >= 0 && y < H && xc >= 0 && xc < W) v = 8.f * disp[(b * H + y) * W + xc];
        d8s[tid] = v;
    }

    f32x4 zf = {0.f, 0.f, 0.f, 0.f};
    f32x4 acc[4][9];
#pragma unroll
    for (int m = 0; m < 4; ++m)
#pragma unroll
        for (int k = 0; k < 9; ++k) acc[m][k] = zf;

    // this wave's weight stream: [18 s][9 k][1024B], lane slice = lane*16 B
    const _Float16* wp = (const _Float16*)ws_c + (size_t)wid * 82944 + lane * 8;

    // ring start offset: decorrelate co-resident blocks' phases
    const int lb = (blockIdx.z * 20 + blockIdx.y) * 10 + blockIdx.x;
    const int s0 = (lb * 7) % 18;

    half8 bf[9];
#pragma unroll
    for (int k = 0; k < 9; ++k) bf[k] = *(const half8*)(wp + (size_t)s0 * 4608 + k * 512);

    __syncthreads();   // xs, d8s ready

    int s = s0;
#pragma unroll 2
    for (int i = 0; i < 18; ++i) {
        int sn = s + 1; if (sn == 18) sn = 0;
        const int t = s >> 1;
        const int dy = t / 3, dx = t - dy * 3;
        const int aslot = (s & 1) * 4 + grp;
        half8 af[4];
#pragma unroll
        for (int mt = 0; mt < 4; ++mt) {
            int wrow = (mt + dy) * 18 + c + dx;
            af[mt] = *(const half8*)&xs[wrow * 64 + (aslot ^ (wrow & 7)) * 8];
        }
        const _Float16* wnext = wp + (size_t)sn * 4608;
#pragma unroll
        for (int k = 0; k < 9; ++k) {
            half8 cur = bf[k];
            // prefetch ring-next step's fragment k (i=17 wraps to s0: unused
            // but always a valid address — no overread needed)
            bf[k] = *(const half8*)(wnext + k * 512);
#pragma unroll
            for (int mt = 0; mt < 4; ++mt)
                acc[mt][k] = __builtin_amdgcn_mfma_f32_16x16x32_f16(
                    af[mt], cur, acc[mt][k], 0, 0, 0);
        }
        s = sn;
    }

    // epilogue: lane-local softmax over 9 k per (pixel, ij)
    const int ij = wid * 16 + c;
    const int oi = ij >> 3, oj = ij & 7;
#pragma unroll
    for (int mt = 0; mt < 4; ++mt) {
#pragma unroll
        for (int r = 0; r < 4; ++r) {
            int pr = mt, pc = grp * 4 + r;
            float pat[9];
#pragma unroll
            for (int k9 = 0; k9 < 9; ++k9) pat[k9] = d8s[(pr + k9 / 3) * 18 + pc + k9 % 3];
            float mx = acc[mt][0][r];
#pragma unroll
            for (int k9 = 1; k9 < 9; ++k9) mx = fmaxf(mx, acc[mt][k9][r]);
            float sum = 0.f, up = 0.f;
#pragma unroll
            for (int k9 = 0; k9 < 9; ++k9) {
                float e = __expf(acc[mt][k9][r] - mx);
                sum += e; up += e * pat[k9];
            }
            int y = ty0 + pr, xc = tx0 + pc;
            out[((size_t)(b * (8 * H) + y * 8 + oi)) * (size_t)(8 * W) + xc * 8 + oj] = up / sum;
        }
    }
}

// ---------------------------------------------------------------------------
extern "C" void kernel_launch(void* const* d_in, const int* in_sizes, int n_in,
                              void* d_out, int out_size, void* d_ws, size_t ws_size,
                              hipStream_t stream)
{
    const float* guidance = (const float*)d_in[0];
    const float* disp     = (const float*)d_in[1];
    const float* conv1_w  = (const float*)d_in[2];
    const float* bn_gamma = (const float*)d_in[3];
    const float* bn_beta  = (const float*)d_in[4];
    const float* bn_mean  = (const float*)d_in[5];
    const float* bn_var   = (const float*)d_in[6];
    const float* conv2_w  = (const float*)d_in[7];
    float* out = (float*)d_out;
    char* ws = (char*)d_ws;
    _Float16* xg = (_Float16*)(ws + XG_OFF);

    prep<<<dim3((576 * 64 + 64 * 32 + 255) / 256), dim3(256), 0, stream>>>(
        conv1_w, conv2_w, ws);
    dim3 grid1(W / 16, H / 8, B_);   // (10, 10, 8)
    conv1_mfma<<<grid1, dim3(256), 0, stream>>>(
        guidance, ws + W1WS_OFF, bn_gamma, bn_beta, bn_mean, bn_var, xg);
    dim3 grid2(W / 16, H / 4, B_);   // (10, 20, 8)
    conv2_mfma<<<grid2, dim3(256), 0, stream>>>(
        xg, ws + CWS_OFF, disp, out);
}